// Round 3
// baseline (124.304 us; speedup 1.0000x reference)
//
#include <hip/hip_runtime.h>

typedef __bf16 bf16_t;
typedef __bf16 bf16x8 __attribute__((ext_vector_type(8)));
typedef __bf16 bf16x4 __attribute__((ext_vector_type(4)));
typedef float f32x4 __attribute__((ext_vector_type(4)));

__device__ __forceinline__ void async16(const void* g, void* l) {
  __builtin_amdgcn_global_load_lds(
      (const __attribute__((address_space(1))) unsigned int*)g,
      (__attribute__((address_space(3))) unsigned int*)l,
      16, 0, 0);
}

// ---------------------------------------------------------------------------
// Fused prep for Bcat (512 x 1024 bf16):
//   blocks 0..255   : convert proj_R (256x1024 f32) -> Bcat rows 256..511
//   blocks 256..511 : LDS-tiled transpose proj_L (1024x256 f32) -> rows 0..255
// ---------------------------------------------------------------------------
__global__ void prep_Bcat(const float* __restrict__ projL,
                          const float* __restrict__ projR,
                          bf16_t* __restrict__ Bcat) {
  const int t = threadIdx.x;
  if (blockIdx.x < 256) {
    int i = blockIdx.x * 256 + t;
    float4 v = ((const float4*)projR)[i];
    bf16x4 o;
    o[0] = (bf16_t)v.x; o[1] = (bf16_t)v.y; o[2] = (bf16_t)v.z; o[3] = (bf16_t)v.w;
    ((bf16x4*)(Bcat + (long)256 * 1024))[i] = o;
  } else {
    __shared__ float tile[32][33];
    const int bb = blockIdx.x - 256;
    const int n0 = (bb & 7) * 32;   // col block in projL (N=256)
    const int k0 = (bb >> 3) * 32;  // row block in projL (K=1024)
    const int tx = t & 31;
    const int ty = t >> 5;  // 0..7
#pragma unroll
    for (int i = 0; i < 32; i += 8)
      tile[ty + i][tx] = projL[(long)(k0 + ty + i) * 256 + n0 + tx];
    __syncthreads();
#pragma unroll
    for (int i = 0; i < 32; i += 8)
      Bcat[(long)(n0 + ty + i) * 1024 + k0 + tx] = (bf16_t)tile[tx][ty + i];
  }
}

// ---------------------------------------------------------------------------
// C(MxN) = A(MxK) @ Bt(NxK)^T, 128x128 tile, 256 thr (4 waves 2x2),
// 4x4 16x16x32 bf16 MFMA per wave. BK=64 DOUBLE-BUFFERED:
//   barrier; prefetch(s+1) [B via global_load_lds; A optionally fp32->bf16
//   via VGPR round-trip, loads issued before compute, cvt+ds_write after];
//   compute(s). One barrier per step; the vmcnt(0) drain at the next barrier
//   finds loads that aged a full compute phase. LDS 64 KB (2 buf x 32 KB).
// LDS sub-tile layout = flat row-major 128x32 bf16 (== m97 staging layout).
// K multiple of 64.
// ---------------------------------------------------------------------------
template <bool A_FP32, bool BF16_OUT>
__global__ __launch_bounds__(256) void gemm_bt(
    const void* __restrict__ A0v, long sA, int lda,
    const bf16_t* __restrict__ B0, long sB, int ldb,
    void* __restrict__ C0, long sC, int ldc,
    int K, int tilesN, const float* __restrict__ bias) {
  const int bz = blockIdx.y;
  const bf16_t* Bt = B0 + (long)bz * sB;
  const int tm = (int)(blockIdx.x / tilesN) * 128;
  const int tn = (int)(blockIdx.x % tilesN) * 128;

  // [buf][sub][128*32]; flat offsets: buf*8192 + sub*4096
  __shared__ __attribute__((aligned(16))) bf16_t As[2 * 2 * 4096];
  __shared__ __attribute__((aligned(16))) bf16_t Bs[2 * 2 * 4096];

  const int t = threadIdx.x;
  const int lane = t & 63;
  const int quad = lane >> 4;
  const int l15 = lane & 15;
  const int wave = t >> 6;
  const int wr = (wave >> 1) * 64;
  const int wc = (wave & 1) * 64;

  // async16 staging thread map (per 128x32 sub-tile): row t>>2, cols (t&3)*8
  const int rS = t >> 2;
  const int cS = (t & 3) * 8;
  const bf16_t* gB = Bt + (long)(tn + rS) * ldb + cS;

  // bf16-A async16 source
  const bf16_t* gA16 = nullptr;
  // fp32-A manual source: thread t -> rows (t>>3)+32i (i=0..3), col chunk t&7
  const float* gA32 = nullptr;
  if constexpr (A_FP32) {
    gA32 = (const float*)A0v + (long)(tm + (t >> 3)) * lda + (t & 7) * 8;
  } else {
    gA16 = (const bf16_t*)A0v + (long)bz * sA + (long)(tm + rS) * lda + cS;
  }

  f32x4 acc[4][4];
#pragma unroll
  for (int i = 0; i < 4; ++i)
#pragma unroll
    for (int j = 0; j < 4; ++j)
      acc[i][j] = (f32x4){0.f, 0.f, 0.f, 0.f};

  const int NS = K >> 6;  // steps of BK=64
  float4 fa[4], fb[4];    // fp32-A prefetch registers (rows +32i)

  // ---- staging helpers (inlined manually via lambdas) ----
  auto stageB = [&](int buf, int ko) {
    const bf16_t* g = gB + ko;
    bf16_t* l = Bs + buf * 8192 + t * 8;
    async16(g, l);                              // sub0 rows 0..63
    async16(g + (long)64 * ldb, l + 2048);      // sub0 rows 64..127
    async16(g + 32, l + 4096);                  // sub1 rows 0..63
    async16(g + 32 + (long)64 * ldb, l + 6144); // sub1 rows 64..127
  };
  auto stageA16 = [&](int buf, int ko) {
    const bf16_t* g = gA16 + ko;
    bf16_t* l = As + buf * 8192 + t * 8;
    async16(g, l);
    async16(g + (long)64 * lda, l + 2048);
    async16(g + 32, l + 4096);
    async16(g + 32 + (long)64 * lda, l + 6144);
  };
  auto loadA32 = [&](int ko) {
#pragma unroll
    for (int i = 0; i < 4; ++i) {
      const float* p = gA32 + ko + (long)32 * i * lda;
      fa[i] = *(const float4*)p;
      fb[i] = *(const float4*)(p + 4);
    }
  };
  auto writeA32 = [&](int buf) {
    const int sub = (t & 7) >> 2;
    const int cin = ((t & 7) & 3) * 8;
#pragma unroll
    for (int i = 0; i < 4; ++i) {
      bf16x8 v;
      v[0] = (bf16_t)fa[i].x; v[1] = (bf16_t)fa[i].y;
      v[2] = (bf16_t)fa[i].z; v[3] = (bf16_t)fa[i].w;
      v[4] = (bf16_t)fb[i].x; v[5] = (bf16_t)fb[i].y;
      v[6] = (bf16_t)fb[i].z; v[7] = (bf16_t)fb[i].w;
      *(bf16x8*)(As + buf * 8192 + sub * 4096 + ((t >> 3) + 32 * i) * 32 + cin) = v;
    }
  };

  // ---- prologue: stage buffer 0 ----
  if constexpr (A_FP32) {
    loadA32(0);
    writeA32(0);
  } else {
    stageA16(0, 0);
  }
  stageB(0, 0);

  for (int s = 0; s < NS; ++s) {
    const int cur = s & 1;
    __syncthreads();  // buf[cur] valid (vmcnt+lgkm drained); buf[cur^1] free

    const bool pf = (s + 1 < NS);
    if (pf) {
      if constexpr (A_FP32) loadA32((s + 1) * 64);  // issue, don't wait
      else stageA16(cur ^ 1, (s + 1) * 64);
      stageB(cur ^ 1, (s + 1) * 64);
    }

    // compute on buf[cur]
#pragma unroll
    for (int kc = 0; kc < 2; ++kc) {
      const bf16_t* Ak = As + cur * 8192 + kc * 4096;
      const bf16_t* Bk = Bs + cur * 8192 + kc * 4096;
      bf16x8 af[4], bv[4];
#pragma unroll
      for (int i = 0; i < 4; ++i)
        af[i] = *(const bf16x8*)(Ak + (wr + i * 16 + l15) * 32 + quad * 8);
#pragma unroll
      for (int j = 0; j < 4; ++j)
        bv[j] = *(const bf16x8*)(Bk + (wc + j * 16 + l15) * 32 + quad * 8);
#pragma unroll
      for (int i = 0; i < 4; ++i)
#pragma unroll
        for (int j = 0; j < 4; ++j)
          acc[i][j] = __builtin_amdgcn_mfma_f32_16x16x32_bf16(af[i], bv[j],
                                                              acc[i][j], 0, 0, 0);
    }

    if (pf) {
      if constexpr (A_FP32) writeA32(cur ^ 1);  // vmcnt wait lands here, post-compute
    }
  }

  // Epilogue. C/D layout (verified m89/m91): col = lane&15, row = quad*4 + reg
  if constexpr (BF16_OUT) {
    bf16_t* C = (bf16_t*)C0 + (long)bz * sC;
#pragma unroll
    for (int i = 0; i < 4; ++i) {
      const int r0 = tm + wr + i * 16 + quad * 4;
#pragma unroll
      for (int j = 0; j < 4; ++j) {
        const int c0 = tn + wc + j * 16 + l15;
#pragma unroll
        for (int r = 0; r < 4; ++r)
          C[(long)(r0 + r) * ldc + c0] = (bf16_t)acc[i][j][r];
      }
    }
  } else {
    float* C = (float*)C0 + (long)bz * sC;
    const float bvadd = bias[0];
#pragma unroll
    for (int i = 0; i < 4; ++i) {
      const int r0 = tm + wr + i * 16 + quad * 4;
#pragma unroll
      for (int j = 0; j < 4; ++j) {
        const int c0 = tn + wc + j * 16 + l15;
#pragma unroll
        for (int r = 0; r < 4; ++r)
          C[(long)(r0 + r) * ldc + c0] = acc[i][j][r] + bvadd;
      }
    }
  }
}

extern "C" void kernel_launch(void* const* d_in, const int* in_sizes, int n_in,
                              void* d_out, int out_size, void* d_ws,
                              size_t ws_size, hipStream_t stream) {
  const float* batch = (const float*)d_in[0];  // (8,1024,1024)
  const float* projL = (const float*)d_in[1];  // (1024,256)
  const float* projR = (const float*)d_in[2];  // (256,1024)
  const float* bias = (const float*)d_in[3];   // (1,)
  float* out = (float*)d_out;                  // (8,1024,1024)

  constexpr int S = 1024, D = 1024, R = 256;

  // workspace: Bcat (512x1024 bf16 = 1 MB) then LR (8192x512 bf16 = 8.4 MB)
  char* ws = (char*)d_ws;
  bf16_t* Bcat = (bf16_t*)ws;
  bf16_t* LR = (bf16_t*)(ws + (long)512 * 1024 * 2);

  // 1) Bcat: rows 0..255 = proj_L^T, rows 256..511 = proj_R (both bf16)
  prep_Bcat<<<512, 256, 0, stream>>>(projL, projR, Bcat);

  // 2) GEMM1 (fused fp32->bf16 on A): LR(8192x512) = batch @ Bcat^T, bf16 out
  gemm_bt<true, true><<<dim3(64 * 4, 1), 256, 0, stream>>>(
      (const void*)batch, 0L, D, Bcat, 0L, D, (void*)LR, 0L, 512, D, 4,
      nullptr);

  // 3) GEMM2: out[b] = left[b](1024x256) @ right[b](1024x256)^T + bias
  //    left = LR[b] cols 0..255, right = LR[b] cols 256..511 (ld=512)
  gemm_bt<false, false><<<dim3(8 * 8, 8), 256, 0, stream>>>(
      (const void*)LR, (long)S * 512, 512, LR + 256, (long)S * 512, 512,
      (void*)out, (long)S * S, S, R, 8, bias);
}

// Round 4
// 117.688 us; speedup vs baseline: 1.0562x; 1.0562x over previous
//
#include <hip/hip_runtime.h>

typedef __bf16 bf16_t;
typedef __bf16 bf16x8 __attribute__((ext_vector_type(8)));
typedef __bf16 bf16x4 __attribute__((ext_vector_type(4)));
typedef float f32x4 __attribute__((ext_vector_type(4)));

__device__ __forceinline__ void async16(const void* g, void* l) {
  __builtin_amdgcn_global_load_lds(
      (const __attribute__((address_space(1))) unsigned int*)g,
      (__attribute__((address_space(3))) unsigned int*)l,
      16, 0, 0);
}

// ---------------------------------------------------------------------------
// Fused prep for Bcat (512 x 1024 bf16):
//   blocks 0..255   : convert proj_R (256x1024 f32) -> Bcat rows 256..511
//   blocks 256..511 : LDS-tiled transpose proj_L (1024x256 f32) -> rows 0..255
// ---------------------------------------------------------------------------
__global__ void prep_Bcat(const float* __restrict__ projL,
                          const float* __restrict__ projR,
                          bf16_t* __restrict__ Bcat) {
  const int t = threadIdx.x;
  if (blockIdx.x < 256) {
    int i = blockIdx.x * 256 + t;
    float4 v = ((const float4*)projR)[i];
    bf16x4 o;
    o[0] = (bf16_t)v.x; o[1] = (bf16_t)v.y; o[2] = (bf16_t)v.z; o[3] = (bf16_t)v.w;
    ((bf16x4*)(Bcat + (long)256 * 1024))[i] = o;
  } else {
    __shared__ float tile[32][33];
    const int bb = blockIdx.x - 256;
    const int n0 = (bb & 7) * 32;   // col block in projL (N=256)
    const int k0 = (bb >> 3) * 32;  // row block in projL (K=1024)
    const int tx = t & 31;
    const int ty = t >> 5;  // 0..7
#pragma unroll
    for (int i = 0; i < 32; i += 8)
      tile[ty + i][tx] = projL[(long)(k0 + ty + i) * 256 + n0 + tx];
    __syncthreads();
#pragma unroll
    for (int i = 0; i < 32; i += 8)
      Bcat[(long)(n0 + ty + i) * 1024 + k0 + tx] = (bf16_t)tile[tx][ty + i];
  }
}

// ---------------------------------------------------------------------------
// GEMM1 (fused fp32->bf16 on A):
//   LR(8192x512 bf16) = batch(8192x1024 f32) @ Bcat(512x1024 bf16)^T
// 128x128 tile, 256 thr (4 waves 2x2), BK=128 single-buffered as 4x BK=32
// sub-tiles (m97 LDS layout, proven). XCD swizzle: tm = bx&63, tn = bx>>6
// so the 4 blocks sharing an A-row-tile are 64 apart -> same XCD -> A
// re-reads hit local L2 (A-tile fp32 = 512 KB, L2 = 4 MiB).
// ---------------------------------------------------------------------------
__global__ __launch_bounds__(256, 1) void gemm1_fusedA(
    const float* __restrict__ batch, const bf16_t* __restrict__ Bcat,
    bf16_t* __restrict__ LR) {
  const int bx = blockIdx.x;
  const int tm = (bx & 63) * 128;  // M tile (8192/128 = 64)
  const int tn = (bx >> 6) * 128;  // N tile (512/128 = 4)

  __shared__ __attribute__((aligned(16))) bf16_t As[4 * 4096];
  __shared__ __attribute__((aligned(16))) bf16_t Bs[4 * 4096];

  const int t = threadIdx.x;
  const int lane = t & 63;
  const int quad = lane >> 4;
  const int l15 = lane & 15;
  const int wave = t >> 6;
  const int wr = (wave >> 1) * 64;
  const int wc = (wave & 1) * 64;

  // B staging (async16, m97 map): per sub-tile row t>>2, cols (t&3)*8
  const int rS = t >> 2;
  const int cS = (t & 3) * 8;
  const bf16_t* gB = Bcat + (long)(tn + rS) * 1024 + cS;
  bf16_t* lB = Bs + t * 8;

  // A fp32 source: thread t -> rows (t>>4)+16i (i=0..7), k-chunk (t&15)*8
  const int rA = t >> 4;          // 0..15
  const int cA = (t & 15) * 8;    // 0,8,..,120
  const float* gA = batch + (long)(tm + rA) * 1024 + cA;
  // LDS dest: sub-tile cA>>5, col-in-sub cA&31, row added per i
  bf16_t* lA = As + (cA >> 5) * 4096 + (cA & 31);

  f32x4 acc[4][4];
#pragma unroll
  for (int i = 0; i < 4; ++i)
#pragma unroll
    for (int j = 0; j < 4; ++j)
      acc[i][j] = (f32x4){0.f, 0.f, 0.f, 0.f};

  for (int s = 0; s < 8; ++s) {  // K=1024, BK=128
    const int k0 = s * 128;
    // B: 8 async16 -> 32 KB tile
#pragma unroll
    for (int kc = 0; kc < 4; ++kc) {
      async16(gB + k0 + kc * 32, lB + kc * 4096);
      async16(gB + k0 + kc * 32 + (long)64 * 1024, lB + kc * 4096 + 2048);
    }
    // A: 16 float4 loads -> cvt -> 8 ds_write_b128
    float4 fa[8], fb[8];
#pragma unroll
    for (int i = 0; i < 8; ++i) {
      const float* p = gA + k0 + (long)16 * i * 1024;
      fa[i] = *(const float4*)p;
      fb[i] = *(const float4*)(p + 4);
    }
#pragma unroll
    for (int i = 0; i < 8; ++i) {
      bf16x8 v;
      v[0] = (bf16_t)fa[i].x; v[1] = (bf16_t)fa[i].y;
      v[2] = (bf16_t)fa[i].z; v[3] = (bf16_t)fa[i].w;
      v[4] = (bf16_t)fb[i].x; v[5] = (bf16_t)fb[i].y;
      v[6] = (bf16_t)fb[i].z; v[7] = (bf16_t)fb[i].w;
      *(bf16x8*)(lA + (rA + 16 * i) * 32) = v;
    }
    __syncthreads();  // drains async16 (vmcnt) + ds_writes (lgkm)

#pragma unroll
    for (int kc = 0; kc < 4; ++kc) {
      const bf16_t* Ak = As + kc * 4096;
      const bf16_t* Bk = Bs + kc * 4096;
      bf16x8 af[4], bv[4];
#pragma unroll
      for (int i = 0; i < 4; ++i)
        af[i] = *(const bf16x8*)(Ak + (wr + i * 16 + l15) * 32 + quad * 8);
#pragma unroll
      for (int j = 0; j < 4; ++j)
        bv[j] = *(const bf16x8*)(Bk + (wc + j * 16 + l15) * 32 + quad * 8);
#pragma unroll
      for (int i = 0; i < 4; ++i)
#pragma unroll
        for (int j = 0; j < 4; ++j)
          acc[i][j] = __builtin_amdgcn_mfma_f32_16x16x32_bf16(af[i], bv[j],
                                                              acc[i][j], 0, 0, 0);
    }
    __syncthreads();
  }

  // Epilogue -> LR bf16 (ldc=512). C/D: col = lane&15, row = quad*4 + reg
#pragma unroll
  for (int i = 0; i < 4; ++i) {
    const int r0 = tm + wr + i * 16 + quad * 4;
#pragma unroll
    for (int j = 0; j < 4; ++j) {
      const int c0 = tn + wc + j * 16 + l15;
#pragma unroll
      for (int r = 0; r < 4; ++r)
        LR[(long)(r0 + r) * 512 + c0] = (bf16_t)acc[i][j][r];
    }
  }
}

// ---------------------------------------------------------------------------
// GEMM2: out[b](1024x1024 f32) = left[b](1024x256) @ right[b](1024x256)^T + bias
// left = LR[b] cols 0..255, right = LR[b] cols 256..511 (ld=512, bf16).
// 128x128 tile, BK=128 single-buffered (K=256 -> 2 steps), async16 staging.
// XCD swizzle: i = bx&7, j = bx>>3 -> blocks sharing a left-row-tile are
// 8 apart -> same XCD.
// ---------------------------------------------------------------------------
__global__ __launch_bounds__(256) void gemm2(const bf16_t* __restrict__ LR,
                                             float* __restrict__ out,
                                             const float* __restrict__ bias) {
  const int bz = blockIdx.y;
  const int bx = blockIdx.x;
  const int tm = (bx & 7) * 128;   // row tile (i)
  const int tn = (bx >> 3) * 128;  // col tile (j)
  const bf16_t* LRb = LR + (long)bz * 1024 * 512;

  __shared__ __attribute__((aligned(16))) bf16_t As[4 * 4096];
  __shared__ __attribute__((aligned(16))) bf16_t Bs[4 * 4096];

  const int t = threadIdx.x;
  const int lane = t & 63;
  const int quad = lane >> 4;
  const int l15 = lane & 15;
  const int wave = t >> 6;
  const int wr = (wave >> 1) * 64;
  const int wc = (wave & 1) * 64;

  const int rS = t >> 2;
  const int cS = (t & 3) * 8;
  const bf16_t* gA = LRb + (long)(tm + rS) * 512 + cS;        // left
  const bf16_t* gB = LRb + (long)(tn + rS) * 512 + 256 + cS;  // right
  bf16_t* lA = As + t * 8;
  bf16_t* lB = Bs + t * 8;

  f32x4 acc[4][4];
#pragma unroll
  for (int i = 0; i < 4; ++i)
#pragma unroll
    for (int j = 0; j < 4; ++j)
      acc[i][j] = (f32x4){0.f, 0.f, 0.f, 0.f};

#pragma unroll
  for (int s = 0; s < 2; ++s) {  // K=256, BK=128
    const int k0 = s * 128;
#pragma unroll
    for (int kc = 0; kc < 4; ++kc) {
      const int ko = k0 + kc * 32;
      async16(gA + ko, lA + kc * 4096);
      async16(gA + ko + (long)64 * 512, lA + kc * 4096 + 2048);
      async16(gB + ko, lB + kc * 4096);
      async16(gB + ko + (long)64 * 512, lB + kc * 4096 + 2048);
    }
    __syncthreads();

#pragma unroll
    for (int kc = 0; kc < 4; ++kc) {
      const bf16_t* Ak = As + kc * 4096;
      const bf16_t* Bk = Bs + kc * 4096;
      bf16x8 af[4], bv[4];
#pragma unroll
      for (int i = 0; i < 4; ++i)
        af[i] = *(const bf16x8*)(Ak + (wr + i * 16 + l15) * 32 + quad * 8);
#pragma unroll
      for (int j = 0; j < 4; ++j)
        bv[j] = *(const bf16x8*)(Bk + (wc + j * 16 + l15) * 32 + quad * 8);
#pragma unroll
      for (int i = 0; i < 4; ++i)
#pragma unroll
        for (int j = 0; j < 4; ++j)
          acc[i][j] = __builtin_amdgcn_mfma_f32_16x16x32_bf16(af[i], bv[j],
                                                              acc[i][j], 0, 0, 0);
    }
    __syncthreads();
  }

  float* C = out + (long)bz * 1024 * 1024;
  const float bvadd = bias[0];
#pragma unroll
  for (int i = 0; i < 4; ++i) {
    const int r0 = tm + wr + i * 16 + quad * 4;
#pragma unroll
    for (int j = 0; j < 4; ++j) {
      const int c0 = tn + wc + j * 16 + l15;
#pragma unroll
      for (int r = 0; r < 4; ++r)
        C[(long)(r0 + r) * 1024 + c0] = acc[i][j][r] + bvadd;
    }
  }
}

extern "C" void kernel_launch(void* const* d_in, const int* in_sizes, int n_in,
                              void* d_out, int out_size, void* d_ws,
                              size_t ws_size, hipStream_t stream) {
  const float* batch = (const float*)d_in[0];  // (8,1024,1024)
  const float* projL = (const float*)d_in[1];  // (1024,256)
  const float* projR = (const float*)d_in[2];  // (256,1024)
  const float* bias = (const float*)d_in[3];   // (1,)
  float* out = (float*)d_out;                  // (8,1024,1024)

  // workspace: Bcat (512x1024 bf16 = 1 MB) then LR (8192x512 bf16 = 8.4 MB)
  char* ws = (char*)d_ws;
  bf16_t* Bcat = (bf16_t*)ws;
  bf16_t* LR = (bf16_t*)(ws + (long)512 * 1024 * 2);

  // 1) Bcat: rows 0..255 = proj_L^T, rows 256..511 = proj_R (both bf16)
  prep_Bcat<<<512, 256, 0, stream>>>(projL, projR, Bcat);

  // 2) GEMM1: LR = batch @ Bcat^T (fp32 A converted in-flight, XCD swizzle)
  gemm1_fusedA<<<256, 256, 0, stream>>>(batch, Bcat, LR);

  // 3) GEMM2: out[b] = left[b] @ right[b]^T + bias (XCD swizzle)
  gemm2<<<dim3(64, 8), 256, 0, stream>>>(LR, out, bias);
}

// Round 5
// 113.723 us; speedup vs baseline: 1.0930x; 1.0349x over previous
//
#include <hip/hip_runtime.h>

typedef __bf16 bf16_t;
typedef __bf16 bf16x8 __attribute__((ext_vector_type(8)));
typedef __bf16 bf16x4 __attribute__((ext_vector_type(4)));
typedef float f32x4 __attribute__((ext_vector_type(4)));

__device__ __forceinline__ void async16(const void* g, void* l) {
  __builtin_amdgcn_global_load_lds(
      (const __attribute__((address_space(1))) unsigned int*)g,
      (__attribute__((address_space(3))) unsigned int*)l,
      16, 0, 0);
}

// ---------------------------------------------------------------------------
// Fused prep for Bcat (512 x 1024 bf16):
//   blocks 0..255   : convert proj_R (256x1024 f32) -> Bcat rows 256..511
//   blocks 256..511 : LDS-tiled transpose proj_L (1024x256 f32) -> rows 0..255
// ---------------------------------------------------------------------------
__global__ void prep_Bcat(const float* __restrict__ projL,
                          const float* __restrict__ projR,
                          bf16_t* __restrict__ Bcat) {
  const int t = threadIdx.x;
  if (blockIdx.x < 256) {
    int i = blockIdx.x * 256 + t;
    float4 v = ((const float4*)projR)[i];
    bf16x4 o;
    o[0] = (bf16_t)v.x; o[1] = (bf16_t)v.y; o[2] = (bf16_t)v.z; o[3] = (bf16_t)v.w;
    ((bf16x4*)(Bcat + (long)256 * 1024))[i] = o;
  } else {
    __shared__ float tile[32][33];
    const int bb = blockIdx.x - 256;
    const int n0 = (bb & 7) * 32;   // col block in projL (N=256)
    const int k0 = (bb >> 3) * 32;  // row block in projL (K=1024)
    const int tx = t & 31;
    const int ty = t >> 5;  // 0..7
#pragma unroll
    for (int i = 0; i < 32; i += 8)
      tile[ty + i][tx] = projL[(long)(k0 + ty + i) * 256 + n0 + tx];
    __syncthreads();
#pragma unroll
    for (int i = 0; i < 32; i += 8)
      Bcat[(long)(n0 + ty + i) * 1024 + k0 + tx] = (bf16_t)tile[tx][ty + i];
  }
}

// ---------------------------------------------------------------------------
// GEMM1 (fused fp32->bf16 on A):
//   LR(8192x512 bf16) = batch(8192x1024 f32) @ Bcat(512x1024 bf16)^T
// M-SPLIT vs R4: 64x128 tile, 512 blocks -> 2 blocks/CU so staging of one
// block overlaps compute of its CU-partner (m114 mechanism; R4's 256-block
// grid was pinned at 1 block/CU with fully-exposed stage latency).
// 256 thr (4 waves, 2Mx2N -> 32x64 wave tile, acc 2x4). BK=128 as 4x BK=32
// sub-tiles (m97 layout). LDS = 16 KB A + 32 KB B = 48 KB.
// XCD swizzle: tm = bx&127, tn = bx>>7; the 4 blocks sharing an A row-tile
// are 128 apart (128 % 8 == 0 -> same XCD) -> A re-reads hit local L2.
// ---------------------------------------------------------------------------
__global__ __launch_bounds__(256, 2) void gemm1_fusedA(
    const float* __restrict__ batch, const bf16_t* __restrict__ Bcat,
    bf16_t* __restrict__ LR) {
  const int bx = blockIdx.x;
  const int tm = (bx & 127) * 64;  // M tile (8192/64 = 128)
  const int tn = (bx >> 7) * 128;  // N tile (512/128 = 4)

  __shared__ __attribute__((aligned(16))) bf16_t As[4 * 2048];  // 64 x 128
  __shared__ __attribute__((aligned(16))) bf16_t Bs[4 * 4096];  // 128 x 128

  const int t = threadIdx.x;
  const int lane = t & 63;
  const int quad = lane >> 4;
  const int l15 = lane & 15;
  const int wave = t >> 6;
  const int wr = (wave >> 1) * 32;  // 0 / 32  (M)
  const int wc = (wave & 1) * 64;   // 0 / 64  (N)

  // B staging (async16, m97 map): per 128x32 sub-tile row t>>2, cols (t&3)*8
  const int rS = t >> 2;
  const int cS = (t & 3) * 8;
  const bf16_t* gB = Bcat + (long)(tn + rS) * 1024 + cS;
  bf16_t* lB = Bs + t * 8;

  // A fp32 source: thread t -> rows (t>>4)+16i (i=0..3), k-chunk (t&15)*8
  const int rA = t >> 4;        // 0..15
  const int cA = (t & 15) * 8;  // 0,8,..,120
  const float* gA = batch + (long)(tm + rA) * 1024 + cA;
  // LDS dest: sub-tile cA>>5 (2048 elem each), col cA&31, row added per i
  bf16_t* lA = As + (cA >> 5) * 2048 + (cA & 31);

  f32x4 acc[2][4];
#pragma unroll
  for (int i = 0; i < 2; ++i)
#pragma unroll
    for (int j = 0; j < 4; ++j)
      acc[i][j] = (f32x4){0.f, 0.f, 0.f, 0.f};

  for (int s = 0; s < 8; ++s) {  // K=1024, BK=128
    const int k0 = s * 128;
    // A: 8 float4 loads (issue first: HBM latency), then B async16 (L2-hot)
    float4 fa[4], fb[4];
#pragma unroll
    for (int i = 0; i < 4; ++i) {
      const float* p = gA + k0 + (long)16 * i * 1024;
      fa[i] = *(const float4*)p;
      fb[i] = *(const float4*)(p + 4);
    }
#pragma unroll
    for (int kc = 0; kc < 4; ++kc) {
      async16(gB + k0 + kc * 32, lB + kc * 4096);
      async16(gB + k0 + kc * 32 + (long)64 * 1024, lB + kc * 4096 + 2048);
    }
    // cvt + 4 ds_write_b128 (waits A loads here, after all issues)
#pragma unroll
    for (int i = 0; i < 4; ++i) {
      bf16x8 v;
      v[0] = (bf16_t)fa[i].x; v[1] = (bf16_t)fa[i].y;
      v[2] = (bf16_t)fa[i].z; v[3] = (bf16_t)fa[i].w;
      v[4] = (bf16_t)fb[i].x; v[5] = (bf16_t)fb[i].y;
      v[6] = (bf16_t)fb[i].z; v[7] = (bf16_t)fb[i].w;
      *(bf16x8*)(lA + (rA + 16 * i) * 32) = v;
    }
    __syncthreads();  // drains async16 (vmcnt) + ds_writes (lgkm)

#pragma unroll
    for (int kc = 0; kc < 4; ++kc) {
      const bf16_t* Ak = As + kc * 2048;
      const bf16_t* Bk = Bs + kc * 4096;
      bf16x8 af[2], bv[4];
#pragma unroll
      for (int i = 0; i < 2; ++i)
        af[i] = *(const bf16x8*)(Ak + (wr + i * 16 + l15) * 32 + quad * 8);
#pragma unroll
      for (int j = 0; j < 4; ++j)
        bv[j] = *(const bf16x8*)(Bk + (wc + j * 16 + l15) * 32 + quad * 8);
#pragma unroll
      for (int i = 0; i < 2; ++i)
#pragma unroll
        for (int j = 0; j < 4; ++j)
          acc[i][j] = __builtin_amdgcn_mfma_f32_16x16x32_bf16(af[i], bv[j],
                                                              acc[i][j], 0, 0, 0);
    }
    __syncthreads();
  }

  // Epilogue -> LR bf16 (ldc=512). C/D: col = lane&15, row = quad*4 + reg
#pragma unroll
  for (int i = 0; i < 2; ++i) {
    const int r0 = tm + wr + i * 16 + quad * 4;
#pragma unroll
    for (int j = 0; j < 4; ++j) {
      const int c0 = tn + wc + j * 16 + l15;
#pragma unroll
      for (int r = 0; r < 4; ++r)
        LR[(long)(r0 + r) * 512 + c0] = (bf16_t)acc[i][j][r];
    }
  }
}

// ---------------------------------------------------------------------------
// GEMM2: out[b](1024x1024 f32) = left[b](1024x256) @ right[b](1024x256)^T + bias
// left = LR[b] cols 0..255, right = LR[b] cols 256..511 (ld=512, bf16).
// 128x128 tile, BK=128 single-buffered (K=256 -> 2 steps), async16 staging.
// XCD swizzle: i = bx&7, j = bx>>3 -> blocks sharing a left-row-tile are
// 8 apart -> same XCD.
// ---------------------------------------------------------------------------
__global__ __launch_bounds__(256) void gemm2(const bf16_t* __restrict__ LR,
                                             float* __restrict__ out,
                                             const float* __restrict__ bias) {
  const int bz = blockIdx.y;
  const int bx = blockIdx.x;
  const int tm = (bx & 7) * 128;   // row tile (i)
  const int tn = (bx >> 3) * 128;  // col tile (j)
  const bf16_t* LRb = LR + (long)bz * 1024 * 512;

  __shared__ __attribute__((aligned(16))) bf16_t As[4 * 4096];
  __shared__ __attribute__((aligned(16))) bf16_t Bs[4 * 4096];

  const int t = threadIdx.x;
  const int lane = t & 63;
  const int quad = lane >> 4;
  const int l15 = lane & 15;
  const int wave = t >> 6;
  const int wr = (wave >> 1) * 64;
  const int wc = (wave & 1) * 64;

  const int rS = t >> 2;
  const int cS = (t & 3) * 8;
  const bf16_t* gA = LRb + (long)(tm + rS) * 512 + cS;        // left
  const bf16_t* gB = LRb + (long)(tn + rS) * 512 + 256 + cS;  // right
  bf16_t* lA = As + t * 8;
  bf16_t* lB = Bs + t * 8;

  f32x4 acc[4][4];
#pragma unroll
  for (int i = 0; i < 4; ++i)
#pragma unroll
    for (int j = 0; j < 4; ++j)
      acc[i][j] = (f32x4){0.f, 0.f, 0.f, 0.f};

#pragma unroll
  for (int s = 0; s < 2; ++s) {  // K=256, BK=128
    const int k0 = s * 128;
#pragma unroll
    for (int kc = 0; kc < 4; ++kc) {
      const int ko = k0 + kc * 32;
      async16(gA + ko, lA + kc * 4096);
      async16(gA + ko + (long)64 * 512, lA + kc * 4096 + 2048);
      async16(gB + ko, lB + kc * 4096);
      async16(gB + ko + (long)64 * 512, lB + kc * 4096 + 2048);
    }
    __syncthreads();

#pragma unroll
    for (int kc = 0; kc < 4; ++kc) {
      const bf16_t* Ak = As + kc * 4096;
      const bf16_t* Bk = Bs + kc * 4096;
      bf16x8 af[4], bv[4];
#pragma unroll
      for (int i = 0; i < 4; ++i)
        af[i] = *(const bf16x8*)(Ak + (wr + i * 16 + l15) * 32 + quad * 8);
#pragma unroll
      for (int j = 0; j < 4; ++j)
        bv[j] = *(const bf16x8*)(Bk + (wc + j * 16 + l15) * 32 + quad * 8);
#pragma unroll
      for (int i = 0; i < 4; ++i)
#pragma unroll
        for (int j = 0; j < 4; ++j)
          acc[i][j] = __builtin_amdgcn_mfma_f32_16x16x32_bf16(af[i], bv[j],
                                                              acc[i][j], 0, 0, 0);
    }
    __syncthreads();
  }

  float* C = out + (long)bz * 1024 * 1024;
  const float bvadd = bias[0];
#pragma unroll
  for (int i = 0; i < 4; ++i) {
    const int r0 = tm + wr + i * 16 + quad * 4;
#pragma unroll
    for (int j = 0; j < 4; ++j) {
      const int c0 = tn + wc + j * 16 + l15;
#pragma unroll
      for (int r = 0; r < 4; ++r)
        C[(long)(r0 + r) * 1024 + c0] = acc[i][j][r] + bvadd;
    }
  }
}

extern "C" void kernel_launch(void* const* d_in, const int* in_sizes, int n_in,
                              void* d_out, int out_size, void* d_ws,
                              size_t ws_size, hipStream_t stream) {
  const float* batch = (const float*)d_in[0];  // (8,1024,1024)
  const float* projL = (const float*)d_in[1];  // (1024,256)
  const float* projR = (const float*)d_in[2];  // (256,1024)
  const float* bias = (const float*)d_in[3];   // (1,)
  float* out = (float*)d_out;                  // (8,1024,1024)

  // workspace: Bcat (512x1024 bf16 = 1 MB) then LR (8192x512 bf16 = 8.4 MB)
  char* ws = (char*)d_ws;
  bf16_t* Bcat = (bf16_t*)ws;
  bf16_t* LR = (bf16_t*)(ws + (long)512 * 1024 * 2);

  // 1) Bcat: rows 0..255 = proj_L^T, rows 256..511 = proj_R (both bf16)
  prep_Bcat<<<512, 256, 0, stream>>>(projL, projR, Bcat);

  // 2) GEMM1: LR = batch @ Bcat^T (fp32 A converted in-flight; 512 blocks
  //    = 2 blocks/CU for cross-block latency hiding; XCD swizzle)
  gemm1_fusedA<<<512, 256, 0, stream>>>(batch, Bcat, LR);

  // 3) GEMM2: out[b] = left[b] @ right[b]^T + bias (XCD swizzle)
  gemm2<<<dim3(64, 8), 256, 0, stream>>>(LR, out, bias);
}

// Round 7
// 111.188 us; speedup vs baseline: 1.1180x; 1.0228x over previous
//
#include <hip/hip_runtime.h>

typedef __bf16 bf16_t;
typedef __bf16 bf16x8 __attribute__((ext_vector_type(8)));
typedef __bf16 bf16x4 __attribute__((ext_vector_type(4)));
typedef float f32x4 __attribute__((ext_vector_type(4)));

__device__ __forceinline__ void async16(const void* g, void* l) {
  __builtin_amdgcn_global_load_lds(
      (const __attribute__((address_space(1))) unsigned int*)g,
      (__attribute__((address_space(3))) unsigned int*)l,
      16, 0, 0);
}

// ---------------------------------------------------------------------------
// Fused prep for Bcat (512 x 1024 bf16):
//   blocks 0..255   : convert proj_R (256x1024 f32) -> Bcat rows 256..511
//   blocks 256..511 : LDS-tiled transpose proj_L (1024x256 f32) -> rows 0..255
// ---------------------------------------------------------------------------
__global__ void prep_Bcat(const float* __restrict__ projL,
                          const float* __restrict__ projR,
                          bf16_t* __restrict__ Bcat) {
  const int t = threadIdx.x;
  if (blockIdx.x < 256) {
    int i = blockIdx.x * 256 + t;
    float4 v = ((const float4*)projR)[i];
    bf16x4 o;
    o[0] = (bf16_t)v.x; o[1] = (bf16_t)v.y; o[2] = (bf16_t)v.z; o[3] = (bf16_t)v.w;
    ((bf16x4*)(Bcat + (long)256 * 1024))[i] = o;
  } else {
    __shared__ float tile[32][33];
    const int bb = blockIdx.x - 256;
    const int n0 = (bb & 7) * 32;   // col block in projL (N=256)
    const int k0 = (bb >> 3) * 32;  // row block in projL (K=1024)
    const int tx = t & 31;
    const int ty = t >> 5;  // 0..7
#pragma unroll
    for (int i = 0; i < 32; i += 8)
      tile[ty + i][tx] = projL[(long)(k0 + ty + i) * 256 + n0 + tx];
    __syncthreads();
#pragma unroll
    for (int i = 0; i < 32; i += 8)
      Bcat[(long)(n0 + ty + i) * 1024 + k0 + tx] = (bf16_t)tile[tx][ty + i];
  }
}

// ---------------------------------------------------------------------------
// GEMM1 (fused fp32->bf16 on A):
//   LR(8192x512 bf16) = batch(8192x1024 f32) @ Bcat(512x1024 bf16)^T
// 64x128 tile, 512 blocks -> 2 blocks/CU (cross-block latency hiding, m114).
// 256 thr (4 waves, 2Mx2N -> 32x64 wave tile, acc 2x4). BK=128 as 4x BK=32
// sub-tiles (m97 layout). LDS = 16 KB A + 32 KB B = 48 KB.
// XCD swizzle: tm = bx&127, tn = bx>>7; the 4 blocks sharing an A row-tile
// are 128 apart (128 % 8 == 0 -> same XCD) -> A re-reads hit local L2.
// ---------------------------------------------------------------------------
__global__ __launch_bounds__(256, 2) void gemm1_fusedA(
    const float* __restrict__ batch, const bf16_t* __restrict__ Bcat,
    bf16_t* __restrict__ LR) {
  const int bx = blockIdx.x;
  const int tm = (bx & 127) * 64;  // M tile (8192/64 = 128)
  const int tn = (bx >> 7) * 128;  // N tile (512/128 = 4)

  __shared__ __attribute__((aligned(16))) bf16_t As[4 * 2048];  // 64 x 128
  __shared__ __attribute__((aligned(16))) bf16_t Bs[4 * 4096];  // 128 x 128

  const int t = threadIdx.x;
  const int lane = t & 63;
  const int quad = lane >> 4;
  const int l15 = lane & 15;
  const int wave = t >> 6;
  const int wr = (wave >> 1) * 32;  // 0 / 32  (M)
  const int wc = (wave & 1) * 64;   // 0 / 64  (N)

  // B staging (async16, m97 map): per 128x32 sub-tile row t>>2, cols (t&3)*8
  const int rS = t >> 2;
  const int cS = (t & 3) * 8;
  const bf16_t* gB = Bcat + (long)(tn + rS) * 1024 + cS;
  bf16_t* lB = Bs + t * 8;

  // A fp32 source: thread t -> rows (t>>4)+16i (i=0..3), k-chunk (t&15)*8
  const int rA = t >> 4;        // 0..15
  const int cA = (t & 15) * 8;  // 0,8,..,120
  const float* gA = batch + (long)(tm + rA) * 1024 + cA;
  // LDS dest: sub-tile cA>>5 (2048 elem each), col cA&31, row added per i
  bf16_t* lA = As + (cA >> 5) * 2048 + (cA & 31);

  f32x4 acc[2][4];
#pragma unroll
  for (int i = 0; i < 2; ++i)
#pragma unroll
    for (int j = 0; j < 4; ++j)
      acc[i][j] = (f32x4){0.f, 0.f, 0.f, 0.f};

  for (int s = 0; s < 8; ++s) {  // K=1024, BK=128
    const int k0 = s * 128;
    // A: 8 float4 loads (issue first: HBM latency), then B async16 (L2-hot)
    float4 fa[4], fb[4];
#pragma unroll
    for (int i = 0; i < 4; ++i) {
      const float* p = gA + k0 + (long)16 * i * 1024;
      fa[i] = *(const float4*)p;
      fb[i] = *(const float4*)(p + 4);
    }
#pragma unroll
    for (int kc = 0; kc < 4; ++kc) {
      async16(gB + k0 + kc * 32, lB + kc * 4096);
      async16(gB + k0 + kc * 32 + (long)64 * 1024, lB + kc * 4096 + 2048);
    }
    // cvt + 4 ds_write_b128 (waits A loads here, after all issues)
#pragma unroll
    for (int i = 0; i < 4; ++i) {
      bf16x8 v;
      v[0] = (bf16_t)fa[i].x; v[1] = (bf16_t)fa[i].y;
      v[2] = (bf16_t)fa[i].z; v[3] = (bf16_t)fa[i].w;
      v[4] = (bf16_t)fb[i].x; v[5] = (bf16_t)fb[i].y;
      v[6] = (bf16_t)fb[i].z; v[7] = (bf16_t)fb[i].w;
      *(bf16x8*)(lA + (rA + 16 * i) * 32) = v;
    }
    __syncthreads();  // drains async16 (vmcnt) + ds_writes (lgkm)

#pragma unroll
    for (int kc = 0; kc < 4; ++kc) {
      const bf16_t* Ak = As + kc * 2048;
      const bf16_t* Bk = Bs + kc * 4096;
      bf16x8 af[2], bv[4];
#pragma unroll
      for (int i = 0; i < 2; ++i)
        af[i] = *(const bf16x8*)(Ak + (wr + i * 16 + l15) * 32 + quad * 8);
#pragma unroll
      for (int j = 0; j < 4; ++j)
        bv[j] = *(const bf16x8*)(Bk + (wc + j * 16 + l15) * 32 + quad * 8);
#pragma unroll
      for (int i = 0; i < 2; ++i)
#pragma unroll
        for (int j = 0; j < 4; ++j)
          acc[i][j] = __builtin_amdgcn_mfma_f32_16x16x32_bf16(af[i], bv[j],
                                                              acc[i][j], 0, 0, 0);
    }
    __syncthreads();
  }

  // Epilogue -> LR bf16 (ldc=512). C/D: col = lane&15, row = quad*4 + reg
#pragma unroll
  for (int i = 0; i < 2; ++i) {
    const int r0 = tm + wr + i * 16 + quad * 4;
#pragma unroll
    for (int j = 0; j < 4; ++j) {
      const int c0 = tn + wc + j * 16 + l15;
#pragma unroll
      for (int r = 0; r < 4; ++r)
        LR[(long)(r0 + r) * 512 + c0] = (bf16_t)acc[i][j][r];
    }
  }
}

// ---------------------------------------------------------------------------
// GEMM2: out[b](1024x1024 f32) = left[b](1024x256) @ right[b](1024x256)^T + bias
// left = LR[b] cols 0..255, right = LR[b] cols 256..511 (ld=512, bf16).
// 128x128 tile, BK=128 single-buffered (K=256 -> 2 steps), async16 staging.
// Flat 512-block grid, BATCH-to-XCD pinning: b = bx&7, tile = bx>>3.
// All 64 tiles of batch b sit at bx == b (mod 8) -> one XCD -> its 2 MB
// left/right slice is fetched once into that XCD's L2 and re-read locally
// (R5's dim3(64,8) grid scattered each batch over all 8 XCDs -> L3 traffic).
// Row-tile sharers are 64 apart -> also same XCD.
// ---------------------------------------------------------------------------
__global__ __launch_bounds__(256) void gemm2(const bf16_t* __restrict__ LR,
                                             float* __restrict__ out,
                                             const float* __restrict__ bias) {
  const int bx = blockIdx.x;
  const int bz = bx & 7;         // batch -> XCD
  const int tile = bx >> 3;      // 0..63
  const int tm = (tile & 7) * 128;   // row tile (i)
  const int tn = (tile >> 3) * 128;  // col tile (j)
  const bf16_t* LRb = LR + (long)bz * 1024 * 512;

  __shared__ __attribute__((aligned(16))) bf16_t As[4 * 4096];
  __shared__ __attribute__((aligned(16))) bf16_t Bs[4 * 4096];

  const int t = threadIdx.x;
  const int lane = t & 63;
  const int quad = lane >> 4;
  const int l15 = lane & 15;
  const int wave = t >> 6;
  const int wr = (wave >> 1) * 64;
  const int wc = (wave & 1) * 64;

  const int rS = t >> 2;
  const int cS = (t & 3) * 8;
  const bf16_t* gA = LRb + (long)(tm + rS) * 512 + cS;        // left
  const bf16_t* gB = LRb + (long)(tn + rS) * 512 + 256 + cS;  // right
  bf16_t* lA = As + t * 8;
  bf16_t* lB = Bs + t * 8;

  f32x4 acc[4][4];
#pragma unroll
  for (int i = 0; i < 4; ++i)
#pragma unroll
    for (int j = 0; j < 4; ++j)
      acc[i][j] = (f32x4){0.f, 0.f, 0.f, 0.f};

#pragma unroll
  for (int s = 0; s < 2; ++s) {  // K=256, BK=128
    const int k0 = s * 128;
#pragma unroll
    for (int kc = 0; kc < 4; ++kc) {
      const int ko = k0 + kc * 32;
      async16(gA + ko, lA + kc * 4096);
      async16(gA + ko + (long)64 * 512, lA + kc * 4096 + 2048);
      async16(gB + ko, lB + kc * 4096);
      async16(gB + ko + (long)64 * 512, lB + kc * 4096 + 2048);
    }
    __syncthreads();

#pragma unroll
    for (int kc = 0; kc < 4; ++kc) {
      const bf16_t* Ak = As + kc * 4096;
      const bf16_t* Bk = Bs + kc * 4096;
      bf16x8 af[4], bv[4];
#pragma unroll
      for (int i = 0; i < 4; ++i)
        af[i] = *(const bf16x8*)(Ak + (wr + i * 16 + l15) * 32 + quad * 8);
#pragma unroll
      for (int j = 0; j < 4; ++j)
        bv[j] = *(const bf16x8*)(Bk + (wc + j * 16 + l15) * 32 + quad * 8);
#pragma unroll
      for (int i = 0; i < 4; ++i)
#pragma unroll
        for (int j = 0; j < 4; ++j)
          acc[i][j] = __builtin_amdgcn_mfma_f32_16x16x32_bf16(af[i], bv[j],
                                                              acc[i][j], 0, 0, 0);
    }
    __syncthreads();
  }

  float* C = out + (long)bz * 1024 * 1024;
  const float bvadd = bias[0];
#pragma unroll
  for (int i = 0; i < 4; ++i) {
    const int r0 = tm + wr + i * 16 + quad * 4;
#pragma unroll
    for (int j = 0; j < 4; ++j) {
      const int c0 = tn + wc + j * 16 + l15;
#pragma unroll
      for (int r = 0; r < 4; ++r)
        C[(long)(r0 + r) * 1024 + c0] = acc[i][j][r] + bvadd;
    }
  }
}

extern "C" void kernel_launch(void* const* d_in, const int* in_sizes, int n_in,
                              void* d_out, int out_size, void* d_ws,
                              size_t ws_size, hipStream_t stream) {
  const float* batch = (const float*)d_in[0];  // (8,1024,1024)
  const float* projL = (const float*)d_in[1];  // (1024,256)
  const float* projR = (const float*)d_in[2];  // (256,1024)
  const float* bias = (const float*)d_in[3];   // (1,)
  float* out = (float*)d_out;                  // (8,1024,1024)

  // workspace: Bcat (512x1024 bf16 = 1 MB) then LR (8192x512 bf16 = 8.4 MB)
  char* ws = (char*)d_ws;
  bf16_t* Bcat = (bf16_t*)ws;
  bf16_t* LR = (bf16_t*)(ws + (long)512 * 1024 * 2);

  // 1) Bcat: rows 0..255 = proj_L^T, rows 256..511 = proj_R (both bf16)
  prep_Bcat<<<512, 256, 0, stream>>>(projL, projR, Bcat);

  // 2) GEMM1: LR = batch @ Bcat^T (fp32 A converted in-flight; 512 blocks
  //    = 2 blocks/CU for cross-block latency hiding; XCD swizzle)
  gemm1_fusedA<<<512, 256, 0, stream>>>(batch, Bcat, LR);

  // 3) GEMM2: out[b] = left[b] @ right[b]^T + bias (batch-to-XCD pinning)
  gemm2<<<512, 256, 0, stream>>>(LR, out, bias);
}